// Round 1
// 60.998 us; speedup vs baseline: 1.0224x; 1.0224x over previous
//
#include <hip/hip_runtime.h>
#include <math.h>

#define N 320
#define NF 22
#define BLOCK 256
#define NWAVE (BLOCK / 64)

// wave-width (64) shuffle reduction
__device__ inline float wred(float v) {
#pragma unroll
  for (int o = 32; o > 0; o >>= 1) v += __shfl_down(v, o, 64);
  return v;
}

__global__ __launch_bounds__(BLOCK) void feat_kernel(const float* __restrict__ an,
                                                     const float* __restrict__ coords,
                                                     float* __restrict__ out) {
  const int i = blockIdx.x;
  const int tid = threadIdx.x;
  const int lane = tid & 63;
  const int wave = tid >> 6;

  __shared__ float craw[3 * N];
  __shared__ float4 nA[N];   // dx, dy, dz, 1/r
  __shared__ float2 nB[N];   // fc*exp(-0.1 r^2), fc*exp(-0.5 r^2)
  __shared__ int cnt;
  __shared__ float part[NWAVE][21];

  // ---- vectorized coords staging: 960 floats = 240 float4 ----
  if ((reinterpret_cast<uintptr_t>(coords) & 15u) == 0) {
    if (tid < 240)
      reinterpret_cast<float4*>(craw)[tid] = reinterpret_cast<const float4*>(coords)[tid];
  } else {
    for (int t = tid; t < 3 * N; t += BLOCK) craw[t] = coords[t];
  }
  if (tid == 0) cnt = 0;
  __syncthreads();

  const float xi = craw[3 * i], yi = craw[3 * i + 1], zi = craw[3 * i + 2];
  const float PI_RC = 0.5235987755982988f;  // pi / Rc

  float s[13];
#pragma unroll
  for (int t = 0; t < 13; t++) s[t] = 0.f;

  // ---- phase 1: neighbor scan + ballot-compacted list build ----
  // 320 = 256 + 64: every loop trip is wave-aligned (iter 2 = wave 0 only, full wave)
  for (int j = tid; j < N; j += BLOCK) {
    float dx = xi - craw[3 * j], dy = yi - craw[3 * j + 1], dz = zi - craw[3 * j + 2];
    float r2 = dx * dx + dy * dy + dz * dz;
    bool valid = (j != i) && (r2 < 36.0f);
    unsigned long long m = __ballot(valid);
    int base = 0;
    if (lane == 0 && m) base = atomicAdd(&cnt, __popcll(m));  // 1 atomic / wave-iter
    base = __shfl(base, 0, 64);
    if (valid) {
      float ir = (r2 > 0.f) ? rsqrtf(r2) : 0.f;  // guard matches ref's where(rr>0,...)
      float r = r2 * ir;
      float fc = 0.5f * (__cosf(PI_RC * r) + 1.0f);

      s[0] += fc;  // G1
      // G2 rs=0: eta={0.5,1,2,4} as powers of e1 = exp(-0.5 r^2)
      float e1 = __expf(-0.5f * r2);
      float e2 = e1 * e1, e4 = e2 * e2, e8 = e4 * e4;
      s[1] += e1 * fc; s[2] += e2 * fc; s[3] += e4 * fc; s[4] += e8 * fc;
      // G2 rs=3
      float d3 = r - 3.0f;
      float f1 = __expf(-0.5f * d3 * d3);
      float f2 = f1 * f1, f4 = f2 * f2, f8 = f4 * f4;
      s[5] += f1 * fc; s[6] += f2 * fc; s[7] += f4 * fc; s[8] += f8 * fc;
      // G3: cos(kappa r), kappa={0.5,1,1.5,2} from one sincos(0.5 r)
      float c05, s05;
      __sincosf(0.5f * r, &s05, &c05);
      float c1 = c05 * c05 - s05 * s05;
      float s1 = 2.0f * s05 * c05;
      float c15 = c1 * c05 - s1 * s05;
      float c2 = c1 * c1 - s1 * s1;
      s[9] += c05 * fc; s[10] += c1 * fc; s[11] += c15 * fc; s[12] += c2 * fc;

      int idx = base + __popcll(m & ((1ull << lane) - 1ull));
      nA[idx] = make_float4(dx, dy, dz, ir);
      float w01 = __expf(-0.1f * r2);
      nB[idx] = make_float2(fc * w01, fc * e1);  // exp(-0.5 r^2) reused as eta=0.5 weight
    }
  }
  __syncthreads();

  const int M = cnt;
  const int T = (M * (M - 1)) >> 1;  // unordered pairs a<b (symmetry: ref's 0.5x ordered sum)
  float a[8];
#pragma unroll
  for (int t = 0; t < 8; t++) a[t] = 0.f;

  // ---- phase 2: triplet loop over unordered neighbor pairs (aa < bb) ----
  for (int t = tid; t < T; t += BLOCK) {
    // decode triangular index: bb = largest b with b(b-1)/2 <= t
    float ft = (float)(8 * t + 1);  // exact: < 2^24
    int bb = (int)((1.0f + sqrtf(ft)) * 0.5f);
    while (bb * (bb - 1) / 2 > t) --bb;
    while (bb * (bb + 1) / 2 <= t) ++bb;
    int aa = t - ((bb * (bb - 1)) >> 1);

    float4 A = nA[aa];       // ds_read_b128
    float4 B = nA[bb];       // ds_read_b128
    float2 wa = nB[aa];      // ds_read_b64
    float2 wb = nB[bb];      // ds_read_b64

    float dot = A.x * B.x + A.y * B.y + A.z * B.z;
    float cost = dot * A.w * B.w;
    float q01 = wa.x * wb.x;  // G5 eta=0.1 pair weight
    float q05 = wa.y * wb.y;  // G5 eta=0.5 pair weight
    // c_j - c_k = d_ik - d_ij
    float ex = B.x - A.x, ey = B.y - A.y, ez = B.z - A.z;
    float r2jk = ex * ex + ey * ey + ez * ez;
    float p01 = 0.f, p05 = 0.f;
    if (r2jk < 36.0f) {
      float rjk = sqrtf(r2jk);
      float fcjk = 0.5f * (__cosf(PI_RC * rjk) + 1.0f);
      float g01 = __expf(-0.1f * r2jk);
      float g01_2 = g01 * g01;
      float g05 = g01_2 * g01_2 * g01;
      p01 = q01 * fcjk * g01;
      p05 = q05 * fcjk * g05;
    }
    float c1p = 1.f + cost, c1m = 1.f - cost;
    float c1p2 = c1p * c1p, c1m2 = c1m * c1m;
    float c1p4 = c1p2 * c1p2, c1m4 = c1m2 * c1m2;
    // G4: (eta,zeta,lam) = (0.1,1,+1),(0.1,2,-1),(0.5,4,+1),(0.5,4,-1)
    a[0] += c1p  * p01;
    a[1] += c1m2 * p01;
    a[2] += c1p4 * p05;
    a[3] += c1m4 * p05;
    // G5: same params, no jk factor
    a[4] += c1p  * q01;
    a[5] += c1m2 * q01;
    a[6] += c1p4 * q05;
    a[7] += c1m4 * q05;
  }

  // ---- block reduction of 21 sums ----
  float vals[21];
#pragma unroll
  for (int t = 0; t < 13; t++) vals[t] = s[t];
#pragma unroll
  for (int t = 0; t < 8; t++) vals[13 + t] = a[t];

#pragma unroll
  for (int t = 0; t < 21; t++) {
    float rv = wred(vals[t]);
    if (lane == 0) part[wave][t] = rv;
  }
  __syncthreads();

  if (tid < 21) {
    float tot = part[0][tid] + part[1][tid] + part[2][tid] + part[3][tid];
    // 2^(1-zeta) for zeta = {1,2,4,4}; the ref's extra 0.5 is absorbed by
    // summing unordered pairs instead of ordered ones.
    const float pf[8] = {1.0f, 0.5f, 0.125f, 0.125f, 1.0f, 0.5f, 0.125f, 0.125f};
    if (tid >= 13) tot *= pf[tid - 13];
    out[i * NF + 1 + tid] = tot;
  }
  if (tid == 21) out[i * NF + 0] = an[i];
}

extern "C" void kernel_launch(void* const* d_in, const int* in_sizes, int n_in,
                              void* d_out, int out_size, void* d_ws, size_t ws_size,
                              hipStream_t stream) {
  const float* an = (const float*)d_in[0];      // [320,1] float32
  const float* coords = (const float*)d_in[1];  // [320,3] float32
  float* out = (float*)d_out;                   // [320,22] float32
  feat_kernel<<<N, BLOCK, 0, stream>>>(an, coords, out);
}